// Round 5
// baseline (276.580 us; speedup 1.0000x reference)
//
#include <hip/hip_runtime.h>
#include <hip/hip_fp16.h>

#define B_ 4
#define S_ 2048
#define H_ 1024
#define M_ (B_ * S_)  // 8192 flattened rows of x / q / k / v

typedef _Float16 f16;
typedef _Float16 f16x8 __attribute__((ext_vector_type(8)));
typedef _Float16 f16x4 __attribute__((ext_vector_type(4)));
typedef float f32x4 __attribute__((ext_vector_type(4)));
typedef float f32x16 __attribute__((ext_vector_type(16)));

typedef __attribute__((address_space(3))) unsigned int* lds_u32p;
typedef const __attribute__((address_space(1))) unsigned int* gbl_u32p;

// async global->LDS, 16B per lane; LDS dest is wave-uniform base + lane*16
__device__ __forceinline__ void stage16(const f16* g, f16* l) {
  __builtin_amdgcn_global_load_lds((gbl_u32p)g, (lds_u32p)l, 16, 0, 0);
}

// ---------------------------------------------------------------------------
// One launch: x (8192 blocks) then Wq/Wk/Wv (1024 blocks each) -> fp16 RNE.
__global__ __launch_bounds__(256) void downconvert_all(
    const float* __restrict__ x, const float* __restrict__ W0,
    const float* __restrict__ W1, const float* __restrict__ W2,
    f16* __restrict__ xh, f16* __restrict__ Wh) {
  const int b = blockIdx.x;
  const float* src;
  f16* dst;
  long i;
  if (b < M_ * H_ / 1024) {  // 8192 x-blocks
    src = x; dst = xh;
    i = (long)b * 256 + threadIdx.x;
  } else {
    const int wb = b - M_ * H_ / 1024;
    const int sel = wb >> 10;               // 1024 blocks per W
    src = sel == 0 ? W0 : (sel == 1 ? W1 : W2);
    dst = Wh + (long)sel * H_ * H_;
    i = (long)(wb & 1023) * 256 + threadIdx.x;
  }
  f32x4 v = ((const f32x4*)src)[i];
  f16x4 h;
#pragma unroll
  for (int c = 0; c < 4; c++) h[c] = (f16)v[c];
  ((f16x4*)dst)[i] = h;
}

// ---------------------------------------------------------------------------
// Fused QKV projection, 32x32x16 MFMA edition.
// qkv[sel][m][n] = fp16round( x[m][:] . W_sel[n][:] + b_sel[n] ); pure fp16.
// NT GEMM, 128x128 tile, BK=64 (two 128x32 LDS tiles per matrix per barrier;
// global_load_lds lane ordering identical to BK=32 version).
// Per wave: 64x64 = 2x2 of 32x32, acc = 2x2 f32x16.
// Fragments: A[m=lane&31][k=(lane>>5)*8+j]; C/D col=lane&31,
// row=(reg&3)+8*(reg>>2)+4*(lane>>5)  [measured m74/m101].
// sel==2 (V) written TRANSPOSED to vT[b][h][t] (f16x4 stores along t).
__global__ __launch_bounds__(256, 2)
void qkv_gemm(const f16* __restrict__ xh, const f16* __restrict__ Wh,
              const float* __restrict__ bq, const float* __restrict__ bk,
              const float* __restrict__ bv, f16* __restrict__ qkv,
              f16* __restrict__ vT) {
  __shared__ __align__(16) f16 As[2 * 128 * 32];  // [chunk0 | chunk1]
  __shared__ __align__(16) f16 Bs[2 * 128 * 32];
  const int t = threadIdx.x;
  const int wave = t >> 6, lane = t & 63;
  const int l32 = lane & 31, half = lane >> 5;
  const int wm = (wave & 1) * 64, wn = (wave >> 1) * 64;
  const int sel = blockIdx.y >> 3;             // 0=q 1=k 2=v
  const int ntile = (blockIdx.y & 7) * 128;
  const int mtile = blockIdx.x * 128;

  const f16* Ab = xh + (long)mtile * H_;
  const f16* Bb = Wh + (long)sel * H_ * H_ + (long)ntile * H_;

  const int r0 = t >> 2;        // staging row 0..63
  const int c8 = (t & 3) * 8;   // staging col (halfs)

  f32x16 acc[2][2] = {};

  for (int k0 = 0; k0 < H_; k0 += 64) {
    __syncthreads();
    stage16(Ab + (long)r0 * H_ + k0 + c8,             As + t * 8);
    stage16(Ab + (long)(r0 + 64) * H_ + k0 + c8,      As + 2048 + t * 8);
    stage16(Ab + (long)r0 * H_ + k0 + 32 + c8,        As + 4096 + t * 8);
    stage16(Ab + (long)(r0 + 64) * H_ + k0 + 32 + c8, As + 6144 + t * 8);
    stage16(Bb + (long)r0 * H_ + k0 + c8,             Bs + t * 8);
    stage16(Bb + (long)(r0 + 64) * H_ + k0 + c8,      Bs + 2048 + t * 8);
    stage16(Bb + (long)r0 * H_ + k0 + 32 + c8,        Bs + 4096 + t * 8);
    stage16(Bb + (long)(r0 + 64) * H_ + k0 + 32 + c8, Bs + 6144 + t * 8);
    __syncthreads();
#pragma unroll
    for (int kk = 0; kk < 2; kk++)        // which 128x32 LDS tile
#pragma unroll
      for (int k16 = 0; k16 < 2; k16++) { // which K=16 chunk within it
        const int kb = kk * 4096, kc = k16 * 16 + half * 8;
        f16x8 af[2], bf[2];
#pragma unroll
        for (int i = 0; i < 2; i++) {
          af[i] = *(const f16x8*)&As[kb + (wm + i * 32 + l32) * 32 + kc];
          bf[i] = *(const f16x8*)&Bs[kb + (wn + i * 32 + l32) * 32 + kc];
        }
#pragma unroll
        for (int i = 0; i < 2; i++)
#pragma unroll
          for (int j = 0; j < 2; j++)
            acc[i][j] = __builtin_amdgcn_mfma_f32_32x32x16_f16(af[i], bf[j], acc[i][j], 0, 0, 0);
      }
  }

  const float* bias = sel == 0 ? bq : (sel == 1 ? bk : bv);
  if (sel == 2) {
    // V transposed: vT[(b*H + n)*S + t_pos], b = m>>11, t_pos = m&2047.
#pragma unroll
    for (int jt = 0; jt < 2; jt++) {
      int n = ntile + wn + jt * 32 + l32;
      float bb = bias[n];
#pragma unroll
      for (int it = 0; it < 2; it++)
#pragma unroll
        for (int g = 0; g < 4; g++) {
          int m = mtile + wm + it * 32 + half * 4 + g * 8;
          f16x4 pack;
#pragma unroll
          for (int r = 0; r < 4; r++) pack[r] = (f16)(acc[it][jt][g * 4 + r] + bb);
          *(f16x4*)&vT[((long)(m >> 11) * H_ + n) * S_ + (m & 2047)] = pack;
        }
    }
  } else {
    f16* out = qkv + (long)sel * M_ * H_;
#pragma unroll
    for (int jt = 0; jt < 2; jt++) {
      int n = ntile + wn + jt * 32 + l32;
      float bb = bias[n];
#pragma unroll
      for (int it = 0; it < 2; it++)
#pragma unroll
        for (int g = 0; g < 4; g++) {
          int m = mtile + wm + it * 32 + half * 4 + g * 8;
#pragma unroll
          for (int r = 0; r < 4; r++)
            out[(long)(m + r) * H_ + n] = (f16)(acc[it][jt][g * 4 + r] + bb);
        }
    }
  }
}

// ---------------------------------------------------------------------------
// Generic batched NT fp16 GEMM (32x32x16 MFMA):
// C[z][m][n] = alpha * sum_k A[z][m][k]*B[z][n][k]
// OUT_F16=1: store quantized fp16; OUT_F16=0: store fp32.
template <int OUT_F16>
__global__ __launch_bounds__(256, 2)
void gemm_nt(const f16* __restrict__ A, const f16* __restrict__ Bm,
             void* __restrict__ C, int lda, int ldb, int ldc, int K,
             long sA, long sB, long sC, float alpha) {
  __shared__ __align__(16) f16 As[2 * 128 * 32];
  __shared__ __align__(16) f16 Bs[2 * 128 * 32];
  const int t = threadIdx.x;
  const int wave = t >> 6, lane = t & 63;
  const int l32 = lane & 31, half = lane >> 5;
  const int wm = (wave & 1) * 64, wn = (wave >> 1) * 64;
  const f16* Ab = A + blockIdx.z * sA + (long)blockIdx.x * 128 * lda;
  const f16* Bb = Bm + blockIdx.z * sB + (long)blockIdx.y * 128 * ldb;
  const int r0 = t >> 2, c8 = (t & 3) * 8;
  f32x16 acc[2][2] = {};
  for (int k0 = 0; k0 < K; k0 += 64) {
    __syncthreads();
    stage16(Ab + (long)r0 * lda + k0 + c8,             As + t * 8);
    stage16(Ab + (long)(r0 + 64) * lda + k0 + c8,      As + 2048 + t * 8);
    stage16(Ab + (long)r0 * lda + k0 + 32 + c8,        As + 4096 + t * 8);
    stage16(Ab + (long)(r0 + 64) * lda + k0 + 32 + c8, As + 6144 + t * 8);
    stage16(Bb + (long)r0 * ldb + k0 + c8,             Bs + t * 8);
    stage16(Bb + (long)(r0 + 64) * ldb + k0 + c8,      Bs + 2048 + t * 8);
    stage16(Bb + (long)r0 * ldb + k0 + 32 + c8,        Bs + 4096 + t * 8);
    stage16(Bb + (long)(r0 + 64) * ldb + k0 + 32 + c8, Bs + 6144 + t * 8);
    __syncthreads();
#pragma unroll
    for (int kk = 0; kk < 2; kk++)
#pragma unroll
      for (int k16 = 0; k16 < 2; k16++) {
        const int kb = kk * 4096, kc = k16 * 16 + half * 8;
        f16x8 af[2], bf[2];
#pragma unroll
        for (int i = 0; i < 2; i++) {
          af[i] = *(const f16x8*)&As[kb + (wm + i * 32 + l32) * 32 + kc];
          bf[i] = *(const f16x8*)&Bs[kb + (wn + i * 32 + l32) * 32 + kc];
        }
#pragma unroll
        for (int i = 0; i < 2; i++)
#pragma unroll
          for (int j = 0; j < 2; j++)
            acc[i][j] = __builtin_amdgcn_mfma_f32_32x32x16_f16(af[i], bf[j], acc[i][j], 0, 0, 0);
      }
  }
  const long mb = (long)blockIdx.x * 128 + wm;
  const long nb = (long)blockIdx.y * 128 + wn;
#pragma unroll
  for (int jt = 0; jt < 2; jt++) {
    long n = nb + jt * 32 + l32;
#pragma unroll
    for (int it = 0; it < 2; it++)
#pragma unroll
      for (int g = 0; g < 4; g++) {
        long m = mb + it * 32 + half * 4 + g * 8;
#pragma unroll
        for (int r = 0; r < 4; r++) {
          float v = acc[it][jt][g * 4 + r] * alpha;
          if (OUT_F16)
            ((f16*)C)[blockIdx.z * sC + (m + r) * ldc + n] = (f16)v;
          else
            ((float*)C)[blockIdx.z * sC + (m + r) * ldc + n] = v;
        }
      }
  }
}

// ---------------------------------------------------------------------------
// In-place row softmax over 2048 fp16 scores + quantize to fp16.
__global__ __launch_bounds__(256) void softmax_q(f16* __restrict__ sc) {
  const long row = blockIdx.x;
  f16* p = sc + row * S_;
  const int t = threadIdx.x;
  const int wave = t >> 6, lane = t & 63;
  f16x8 v = ((const f16x8*)p)[t];
  float f[8];
  float m = -3.0e38f;
#pragma unroll
  for (int c = 0; c < 8; c++) { f[c] = (float)v[c]; m = fmaxf(m, f[c]); }
#pragma unroll
  for (int o = 32; o > 0; o >>= 1) m = fmaxf(m, __shfl_xor(m, o));
  __shared__ float redm[4], reds[4];
  if (lane == 0) redm[wave] = m;
  __syncthreads();
  m = fmaxf(fmaxf(redm[0], redm[1]), fmaxf(redm[2], redm[3]));
  float s = 0.f, e[8];
#pragma unroll
  for (int c = 0; c < 8; c++) { e[c] = __expf(f[c] - m); s += e[c]; }
#pragma unroll
  for (int o = 32; o > 0; o >>= 1) s += __shfl_xor(s, o);
  if (lane == 0) reds[wave] = s;
  __syncthreads();
  s = reds[0] + reds[1] + reds[2] + reds[3];
  float inv = 1.0f / s;
  f16x8 ov;
#pragma unroll
  for (int c = 0; c < 8; c++) ov[c] = (f16)(e[c] * inv);
  ((f16x8*)p)[t] = ov;
}

// ---------------------------------------------------------------------------
extern "C" void kernel_launch(void* const* d_in, const int* in_sizes, int n_in,
                              void* d_out, int out_size, void* d_ws, size_t ws_size,
                              hipStream_t stream) {
  (void)in_sizes; (void)n_in; (void)out_size; (void)ws_size;
  const float* x  = (const float*)d_in[0];
  const float* Wq = (const float*)d_in[1];
  const float* bq = (const float*)d_in[2];
  const float* Wk = (const float*)d_in[3];
  const float* bk = (const float*)d_in[4];
  const float* Wv = (const float*)d_in[5];
  const float* bv = (const float*)d_in[6];

  char* ws = (char*)d_ws;
  f16* xh  = (f16*)ws; ws += (size_t)M_ * H_ * 2;          // 16 MiB
  f16* Wh  = (f16*)ws; ws += (size_t)3 * H_ * H_ * 2;      // 6 MiB
  f16* qkv = (f16*)ws; ws += (size_t)2 * M_ * H_ * 2;      // 32 MiB (q, k)
  f16* vT  = (f16*)ws; ws += (size_t)B_ * H_ * S_ * 2;     // 16 MiB
  f16* sc  = (f16*)ws; ws += (size_t)B_ * S_ * S_ * 2;     // 32 MiB (scores, then attn in-place)

  // 1) x, Wq/Wk/Wv -> fp16 in one launch
  downconvert_all<<<M_ * H_ / 1024 + 3 * H_ * H_ / 1024, 256, 0, stream>>>(
      x, Wq, Wk, Wv, xh, Wh);

  // 2) fused QKV projection + bias + quantize; V written transposed
  qkv_gemm<<<dim3(64, 24), 256, 0, stream>>>(xh, Wh, bq, bk, bv, qkv, vT);

  // 3) scores = quantize(q @ k^T / 32), per batch
  gemm_nt<1><<<dim3(16, 16, 4), 256, 0, stream>>>(
      qkv, qkv + (size_t)M_ * H_, sc, H_, H_, S_, H_,
      (long)S_ * H_, (long)S_ * H_, (long)S_ * S_, 0.03125f);

  // 4) attn = quantize(softmax(scores)) in-place
  softmax_q<<<M_, 256, 0, stream>>>(sc);

  // 5) out = attn @ vT^T  (fp32 epilogue straight to d_out)
  gemm_nt<0><<<dim3(16, 8, 4), 256, 0, stream>>>(
      sc, vT, d_out, S_, S_, H_, S_,
      (long)S_ * S_, (long)H_ * S_, (long)S_ * H_, 1.0f);
}